// Round 9
// baseline (2430.941 us; speedup 1.0000x reference)
//
#include <hip/hip_runtime.h>
#include <cstdint>
#include <cstddef>

// Problem constants
#define NB    64      // batch
#define NS    4096    // seq len
#define NH    1024    // hidden
#define NOPSN 8
#define NSTEP 10

#define GRID  256
#define TPB   1024    // 16 waves/block, 1 block/CU -> 4 waves/SIMD

// Workspace layout (float offsets), ~1.8 MB (R3-verified).
// hn/hnT double-buffered by step parity; hnT = k-pair interleave:
// element (k,b) at [(k>>1)*128 + b*2 + (k&1)]
#define OFF_HN0  0u
#define OFF_HN1  65536u
#define OFF_HT0  131072u
#define OFF_HT1  196608u
#define OFF_H    262144u
#define OFF_CAND 327680u   // cand [64][256] float2 (val, idx-as-float)
#define OFF_OPP  360448u   // opp [10][16 jg][64 b][8 o]
#define OFF_CTRL 442368u   // ints: [0]=magic [1]=barrier cnt [2..11]=stopcnt[t]
#define MAGIC    0x1357A5E5

typedef float f2v  __attribute__((ext_vector_type(2)));
typedef float f4v  __attribute__((ext_vector_type(4)));
typedef float f16v __attribute__((ext_vector_type(16)));

__device__ __forceinline__ float bcastf(float v, int l) {
  return __int_as_float(__builtin_amdgcn_readlane(__float_as_int(v), l));
}

// Device-scope grid barrier with full fences (R3-verified).
__device__ __forceinline__ void gridbar(int* cnt, int target) {
  __syncthreads();
  if (threadIdx.x == 0) {
    __threadfence();  // release (device scope)
    __hip_atomic_fetch_add(cnt, 1, __ATOMIC_RELAXED, __HIP_MEMORY_SCOPE_AGENT);
    while (__hip_atomic_load(cnt, __ATOMIC_RELAXED, __HIP_MEMORY_SCOPE_AGENT) < target)
      __builtin_amdgcn_s_sleep(1);
    __threadfence();  // acquire
  }
  __syncthreads();
}

__global__ void __launch_bounds__(TPB, 4)
sys1_kernel(const float* __restrict__ s2a,  const float* __restrict__ Wres,
            const float* __restrict__ bres, const float* __restrict__ Wop,
            const float* __restrict__ bop,  const float* __restrict__ Wx,
            const float* __restrict__ bx,   const float* __restrict__ noise,
            float* __restrict__ out,        float* __restrict__ wsf)
{
  __shared__ float smem[16384];   // 64 KB: cross-wave reductions only

  float* __restrict__ h   = wsf + OFF_H;
  float* __restrict__ opp = wsf + OFF_OPP;
  int* ctrl = (int*)(wsf + OFF_CTRL);
  int* cnt  = ctrl + 1;

  const int tid = threadIdx.x;
  const int blk = blockIdx.x;

  // ---- bootstrap: block 0 inits ctrl (ws is poisoned every launch) ----
  if (blk == 0 && tid == 0) {
    #pragma unroll
    for (int i = 1; i < 32; ++i) ctrl[i] = 0;
    __threadfence();
    __hip_atomic_store(&ctrl[0], (int)MAGIC, __ATOMIC_RELEASE, __HIP_MEMORY_SCOPE_AGENT);
  }
  if (tid == 0) {
    while (__hip_atomic_load(&ctrl[0], __ATOMIC_RELAXED, __HIP_MEMORY_SCOPE_AGENT) != (int)MAGIC)
      __builtin_amdgcn_s_sleep(1);
  }
  __syncthreads();

  const int lane = tid & 63;
  const int wv   = __builtin_amdgcn_readfirstlane(tid >> 6);   // wave 0..15

  const int s0A = blk << 4;            // phase-A s-cols
  const int kbaseA = wv << 6;          // phase-A wave k-slice

  // ---- INIT: hn(0)=0.01*noise[0] into parity-0, h=0, opp[0] ----
  {
    const int jg = blk & 15, bg = blk >> 4;
    if (tid < 256) {
      const int bsel = tid >> 6, jloc = tid & 63;
      const int b = bg * 4 + bsel, j = jg * 64 + jloc;
      float hv = 0.01f * noise[(size_t)b * NH + j];
      (wsf + OFF_HN0)[(size_t)b * NH + j] = hv;
      (wsf + OFF_HT0)[((size_t)(j >> 1)) * 128 + b * 2 + (j & 1)] = hv;
      h[(size_t)b * NH + j] = 0.f;
      const float* wrp = Wop + (size_t)j * NOPSN;
      float opo[8];
      #pragma unroll
      for (int o = 0; o < 8; ++o) opo[o] = hv * wrp[o];
      #pragma unroll
      for (int off = 1; off <= 32; off <<= 1) {
        #pragma unroll
        for (int o = 0; o < 8; ++o) opo[o] += __shfl_xor(opo[o], off);
      }
      if ((tid & 63) == 0) {
        float* od = opp + (size_t)jg * 512 + (size_t)b * 8;
        #pragma unroll
        for (int o = 0; o < 8; ++o) od[o] = opo[o];
      }
    }
  }
  int ep = 0;
  gridbar(cnt, ++ep * GRID);

  for (int st = 0; st < NSTEP; ++st) {
    const float* __restrict__ hn_cur  = wsf + ((st & 1) ? OFF_HN1 : OFF_HN0);
    float* __restrict__       hn_nxt  = wsf + ((st & 1) ? OFF_HN0 : OFF_HN1);
    const float* __restrict__ hnT_cur = wsf + ((st & 1) ? OFF_HT1 : OFF_HT0);
    float* __restrict__       hnT_nxt = wsf + ((st & 1) ? OFF_HT0 : OFF_HT1);

    // ================= PHASE A =================
    // Block: x_logits[16 s][64 b], full K=1024. lane = b.
    // Weights: wave-UNIFORM f16v row loads (Wx is const __restrict__ ->
    // invariant -> scalar-load eligible; weight is the uniform fmac operand,
    // zero VGPR cost). h: per-lane float2 from hnT, chunks of 8 (16 VGPR).
    // 16 v_fmac per 16 MACs — no readlane, live set ~45 regs, no spills.
    {
      const float2* hb = (const float2*)hnT_cur + ((size_t)(kbaseA >> 1)) * 64 + lane;

      // op-argmax for step st (blocks 0..63, wave 0)
      if (blk < NB && tid < 64) {
        const float* ob = opp + (size_t)st * 8192 + (size_t)blk * 8;
        const int o = lane & 7, jgb = lane >> 3;
        float v = ob[(size_t)jgb * 512 + o] + ob[(size_t)(jgb + 8) * 512 + o];
        v += __shfl_xor(v, 8);
        v += __shfl_xor(v, 16);
        v += __shfl_xor(v, 32);
        v += bop[o];
        float bv = bcastf(v, 0); int bo = 0;
        #pragma unroll
        for (int oo = 1; oo < 8; ++oo) {
          float vo = bcastf(v, oo);
          if (vo > bv) { bv = vo; bo = oo; }        // strict > : first-max
        }
        if (lane == 0 && bo == 0) atomicAdd(&ctrl[2 + st], 1);
      }

      float acc[16];
      #pragma unroll
      for (int s = 0; s < 16; ++s) acc[s] = 0.f;

      #pragma unroll 1
      for (int c = 0; c < 4; ++c) {
        float2 hh[8];
        #pragma unroll
        for (int i = 0; i < 8; ++i) hh[i] = hb[(size_t)(c * 8 + i) * 64];
        #pragma unroll
        for (int i = 0; i < 8; ++i) {
          const int k = kbaseA + (c * 8 + i) * 2;
          const f16v w0 = *(const f16v*)(Wx + (size_t)k * NS + s0A);
          const f16v w1 = *(const f16v*)(Wx + (size_t)(k + 1) * NS + s0A);
          #pragma unroll
          for (int s = 0; s < 16; ++s)
            acc[s] += w0[s] * hh[i].x + w1[s] * hh[i].y;
        }
      }

      // cross-wave K reduction: red[16 w][16 s][64 b]
      #pragma unroll
      for (int s = 0; s < 16; ++s)
        smem[wv * 1024 + s * 64 + lane] = acc[s];
      __syncthreads();
      {
        const int s = tid >> 6, b = tid & 63;
        float val = bx[s0A + s];
        #pragma unroll
        for (int w = 0; w < 16; ++w) val += smem[w * 1024 + s * 64 + b];
        __syncthreads();
        smem[s * 64 + b] = val;
        __syncthreads();
        if (tid < 64) {
          const int bb = tid;
          float bv = smem[bb]; int bs = 0;
          #pragma unroll
          for (int s2 = 1; s2 < 16; ++s2) {
            float v2 = smem[s2 * 64 + bb];
            if (v2 > bv) { bv = v2; bs = s2; }      // ascending s: first-max
          }
          float2* cp = (float2*)(wsf + OFF_CAND);
          cp[bb * 256 + blk] = make_float2(bv, __int_as_float(s0A + bs));
        }
      }
    }
    gridbar(cnt, ++ep * GRID);

    // ================= PHASE C =================
    // Block (jg: 64 j, bg: 4 b): h_new full K=2048. lane = j (per-lane
    // coalesced weights), h/s2a wave-uniform f4v loads. Single-buffered
    // 8-k chunks: 8 w + 8 f4v batched (~40 live regs, no spills).
    {
      const int jg = blk & 15, bg = blk >> 4;
      const int j0 = jg << 6, b0 = bg << 2;

      int ptrs[4] = {0, 0, 0, 0};
      if (wv >= 8) {                                 // only s2a half needs ptrs
        const float2* cp = (const float2*)(wsf + OFF_CAND);
        #pragma unroll
        for (int i = 0; i < 4; ++i) {
          const float2* row = cp + (size_t)(b0 + i) * 256;
          float2 c0 = row[lane];
          float bv = c0.x; int bi = __float_as_int(c0.y);
          #pragma unroll
          for (int q = 1; q < 4; ++q) {
            float2 c = row[q * 64 + lane];
            if (c.x > bv) { bv = c.x; bi = __float_as_int(c.y); }
          }
          #pragma unroll
          for (int off = 1; off <= 32; off <<= 1) {
            float ov = __shfl_xor(bv, off);
            int   oi = __shfl_xor(bi, off);
            if (ov > bv || (ov == bv && oi < bi)) { bv = ov; bi = oi; }
          }
          ptrs[i] = __builtin_amdgcn_readfirstlane(bi);
        }
      }
      int done = 0;
      for (int tt = 0; tt < st; ++tt) done |= (ctrl[2 + tt] == NB) ? 1 : 0;

      const int kb = wv << 7;                        // 128 k per wave
      const float *p0, *p1, *p2, *p3;                // wave-uniform bases
      if (wv < 8) {
        p0 = hn_cur + (size_t)(b0 + 0) * NH + kb;
        p1 = hn_cur + (size_t)(b0 + 1) * NH + kb;
        p2 = hn_cur + (size_t)(b0 + 2) * NH + kb;
        p3 = hn_cur + (size_t)(b0 + 3) * NH + kb;
      } else {
        p0 = s2a + ((size_t)(b0 + 0) * NS + ptrs[0]) * NH + (kb - NH);
        p1 = s2a + ((size_t)(b0 + 1) * NS + ptrs[1]) * NH + (kb - NH);
        p2 = s2a + ((size_t)(b0 + 2) * NS + ptrs[2]) * NH + (kb - NH);
        p3 = s2a + ((size_t)(b0 + 3) * NS + ptrs[3]) * NH + (kb - NH);
      }
      const float* wp = Wres + (size_t)kb * NH + j0 + lane;   // per-lane

      float a0 = 0.f, a1 = 0.f, a2 = 0.f, a3 = 0.f;

      #pragma unroll 1
      for (int kc = 0; kc < 128; kc += 8) {
        float w[8];
        f4v q0[2], q1[2], q2[2], q3[2];
        #pragma unroll
        for (int i = 0; i < 8; ++i) w[i] = wp[(size_t)(kc + i) * NH];
        #pragma unroll
        for (int i = 0; i < 2; ++i) {
          q0[i] = *(const f4v*)(p0 + kc + 4 * i);
          q1[i] = *(const f4v*)(p1 + kc + 4 * i);
          q2[i] = *(const f4v*)(p2 + kc + 4 * i);
          q3[i] = *(const f4v*)(p3 + kc + 4 * i);
        }
        #pragma unroll
        for (int i = 0; i < 8; ++i) {
          const float wv_ = w[i];
          a0 += q0[i >> 2][i & 3] * wv_;
          a1 += q1[i >> 2][i & 3] * wv_;
          a2 += q2[i >> 2][i & 3] * wv_;
          a3 += q3[i >> 2][i & 3] * wv_;
        }
      }

      // cross-wave reduce: red[16 w][4 b][64 j]
      smem[wv * 256 + 0 * 64 + lane] = a0;
      smem[wv * 256 + 1 * 64 + lane] = a1;
      smem[wv * 256 + 2 * 64 + lane] = a2;
      smem[wv * 256 + 3 * 64 + lane] = a3;
      __syncthreads();

      if (tid < 256) {
        const int bsel = tid >> 6, jloc = tid & 63;
        float v = bres[j0 + jloc];
        #pragma unroll
        for (int w = 0; w < 16; ++w) v += smem[w * 256 + bsel * 64 + jloc];
        const int b = b0 + bsel, j = j0 + jloc;
        float hold = h[(size_t)b * NH + j];
        float hout = done ? hold : v;
        h[(size_t)b * NH + j] = hout;
        if (st < NSTEP - 1) {
          float hnv = hout + 0.01f * noise[(size_t)(st + 1) * (NB * NH) + (size_t)b * NH + j];
          hn_nxt[(size_t)b * NH + j] = hnv;
          hnT_nxt[((size_t)(j >> 1)) * 128 + b * 2 + (j & 1)] = hnv;
          const float* wrp = Wop + (size_t)j * NOPSN;
          float opo[8];
          #pragma unroll
          for (int o = 0; o < 8; ++o) opo[o] = hnv * wrp[o];
          #pragma unroll
          for (int off = 1; off <= 32; off <<= 1) {
            #pragma unroll
            for (int o = 0; o < 8; ++o) opo[o] += __shfl_xor(opo[o], off);
          }
          if ((tid & 63) == 0) {
            float* od = opp + ((size_t)(st + 1) * 16 + jg) * 512 + (size_t)b * 8;
            #pragma unroll
            for (int o = 0; o < 8; ++o) od[o] = opo[o];
          }
        } else {
          out[(size_t)b * NH + j] = hout;
        }
      }
    }
    if (st < NSTEP - 1) gridbar(cnt, ++ep * GRID);
  }
}

extern "C" void kernel_launch(void* const* d_in, const int* in_sizes, int n_in,
                              void* d_out, int out_size, void* d_ws, size_t ws_size,
                              hipStream_t stream) {
  const float* s2a   = (const float*)d_in[0];
  const float* Wres  = (const float*)d_in[1];
  const float* bres  = (const float*)d_in[2];
  const float* Wop   = (const float*)d_in[3];
  const float* bop   = (const float*)d_in[4];
  const float* Wx    = (const float*)d_in[5];
  const float* bx    = (const float*)d_in[6];
  const float* noise = (const float*)d_in[7];
  float* outp = (float*)d_out;
  float* wsf  = (float*)d_ws;   // needs ~1.8 MB
  hipLaunchKernelGGL(sys1_kernel, dim3(GRID), dim3(TPB), 0, stream,
                     s2a, Wres, bres, Wop, bop, Wx, bx, noise, outp, wsf);
}

// Round 10
// 1865.002 us; speedup vs baseline: 1.3035x; 1.3035x over previous
//
#include <hip/hip_runtime.h>
#include <cstdint>
#include <cstddef>

// Problem constants
#define NB    64      // batch
#define NS    4096    // seq len
#define NH    1024    // hidden
#define NOPSN 8
#define NSTEP 10

// Workspace layout (float offsets), ~1.8 MB (R3-verified layout).
// hn/hnT double-buffered by step parity; hnT = k-pair interleave:
// element (k,b) at [(k>>1)*128 + b*2 + (k&1)]
#define OFF_HN0  0u
#define OFF_HN1  65536u
#define OFF_HT0  131072u
#define OFF_HT1  196608u
#define OFF_H    262144u
#define OFF_CAND 327680u   // cand [64][256] float2 (val, idx-as-float)
#define OFF_OPP  360448u   // opp [10][16 jg][64 b][8 o]
#define OFF_CTRL 442368u   // ints: [2..11]=stopcnt[t]

typedef float f2v  __attribute__((ext_vector_type(2)));
typedef float f4v  __attribute__((ext_vector_type(4)));
typedef float f16v __attribute__((ext_vector_type(16)));

__device__ __forceinline__ float bcastf(float v, int l) {
  return __int_as_float(__builtin_amdgcn_readlane(__float_as_int(v), l));
}

// ============ INIT: hn(0)=0.01*noise[0], hnT(0), h=0, opp[0], ctrl=0 ======
// grid 64 (block = b), 1024 threads (thread = j). Wave wv == jg.
__global__ void __launch_bounds__(1024)
init_kernel(const float* __restrict__ noise, const float* __restrict__ Wop,
            float* __restrict__ wsf)
{
  const int b = blockIdx.x, j = threadIdx.x;
  const int lane = j & 63, jg = j >> 6;
  int* ctrl = (int*)(wsf + OFF_CTRL);
  if (b == 0 && j < NSTEP) ctrl[2 + j] = 0;

  float hv = 0.01f * noise[(size_t)b * NH + j];
  (wsf + OFF_HN0)[(size_t)b * NH + j] = hv;
  (wsf + OFF_HT0)[((size_t)(j >> 1)) * 128 + b * 2 + (j & 1)] = hv;
  (wsf + OFF_H)[(size_t)b * NH + j] = 0.f;

  const float* wrp = Wop + (size_t)j * NOPSN;
  float opo[8];
  #pragma unroll
  for (int o = 0; o < 8; ++o) opo[o] = hv * wrp[o];
  #pragma unroll
  for (int off = 1; off <= 32; off <<= 1) {
    #pragma unroll
    for (int o = 0; o < 8; ++o) opo[o] += __shfl_xor(opo[o], off);
  }
  if (lane == 0) {
    float* od = (wsf + OFF_OPP) + (size_t)jg * 512 + (size_t)b * 8;
    #pragma unroll
    for (int o = 0; o < 8; ++o) od[o] = opo[o];
  }
}

// ============ PHASE A: x_logits[16 s][64 b] + cand + op-argmax ============
// grid 256 (block = 16 s-cols), 1024 thr. lane = b; wave = 64-k slice.
// R9-verified body; sync now provided by kernel boundary (no barrier/fence).
__global__ void __launch_bounds__(1024)
phaseA_kernel(const float* __restrict__ Wx, const float* __restrict__ bx,
              const float* __restrict__ bop, float* __restrict__ wsf, int st)
{
  __shared__ float smem[16384];
  int* ctrl = (int*)(wsf + OFF_CTRL);
  float* __restrict__ opp = wsf + OFF_OPP;
  const float* __restrict__ hnT_cur = wsf + ((st & 1) ? OFF_HT1 : OFF_HT0);

  const int tid = threadIdx.x, blk = blockIdx.x;
  const int lane = tid & 63;
  const int wv = __builtin_amdgcn_readfirstlane(tid >> 6);
  const int s0A = blk << 4;
  const int kbaseA = wv << 6;

  const float2* hb = (const float2*)hnT_cur + ((size_t)(kbaseA >> 1)) * 64 + lane;

  // op-argmax for step st (blocks 0..63, wave 0)
  if (blk < NB && tid < 64) {
    const float* ob = opp + (size_t)st * 8192 + (size_t)blk * 8;
    const int o = lane & 7, jgb = lane >> 3;
    float v = ob[(size_t)jgb * 512 + o] + ob[(size_t)(jgb + 8) * 512 + o];
    v += __shfl_xor(v, 8);
    v += __shfl_xor(v, 16);
    v += __shfl_xor(v, 32);
    v += bop[o];
    float bv = bcastf(v, 0); int bo = 0;
    #pragma unroll
    for (int oo = 1; oo < 8; ++oo) {
      float vo = bcastf(v, oo);
      if (vo > bv) { bv = vo; bo = oo; }            // strict > : first-max
    }
    if (lane == 0 && bo == 0) atomicAdd(&ctrl[2 + st], 1);
  }

  float acc[16];
  #pragma unroll
  for (int s = 0; s < 16; ++s) acc[s] = 0.f;

  #pragma unroll 1
  for (int c = 0; c < 4; ++c) {
    float2 hh[8];
    #pragma unroll
    for (int i = 0; i < 8; ++i) hh[i] = hb[(size_t)(c * 8 + i) * 64];
    #pragma unroll
    for (int i = 0; i < 8; ++i) {
      const int k = kbaseA + (c * 8 + i) * 2;
      const f16v w0 = *(const f16v*)(Wx + (size_t)k * NS + s0A);
      const f16v w1 = *(const f16v*)(Wx + (size_t)(k + 1) * NS + s0A);
      #pragma unroll
      for (int s = 0; s < 16; ++s)
        acc[s] += w0[s] * hh[i].x + w1[s] * hh[i].y;
    }
  }

  // cross-wave K reduction: red[16 w][16 s][64 b]
  #pragma unroll
  for (int s = 0; s < 16; ++s)
    smem[wv * 1024 + s * 64 + lane] = acc[s];
  __syncthreads();
  {
    const int s = tid >> 6, b = tid & 63;
    float val = bx[s0A + s];
    #pragma unroll
    for (int w = 0; w < 16; ++w) val += smem[w * 1024 + s * 64 + b];
    __syncthreads();
    smem[s * 64 + b] = val;
    __syncthreads();
    if (tid < 64) {
      const int bb = tid;
      float bv = smem[bb]; int bs = 0;
      #pragma unroll
      for (int s2 = 1; s2 < 16; ++s2) {
        float v2 = smem[s2 * 64 + bb];
        if (v2 > bv) { bv = v2; bs = s2; }          // ascending s: first-max
      }
      float2* cp = (float2*)(wsf + OFF_CAND);
      cp[bb * 256 + blk] = make_float2(bv, __int_as_float(s0A + bs));
    }
  }
}

// ============ PHASE C: h_new + freeze + next hn/hnT/opp (+ out) ===========
// grid 256: block (jg: 64 j, bg: 4 b), 1024 thr. R9-verified body.
__global__ void __launch_bounds__(1024)
phaseC_kernel(const float* __restrict__ s2a,  const float* __restrict__ Wres,
              const float* __restrict__ bres, const float* __restrict__ Wop,
              const float* __restrict__ noise, float* __restrict__ out,
              float* __restrict__ wsf, int st)
{
  __shared__ float smem[4096];   // [16 w][4 b][64 j]
  int* ctrl = (int*)(wsf + OFF_CTRL);
  float* __restrict__ h   = wsf + OFF_H;
  float* __restrict__ opp = wsf + OFF_OPP;
  const float* __restrict__ hn_cur = wsf + ((st & 1) ? OFF_HN1 : OFF_HN0);
  float* __restrict__       hn_nxt = wsf + ((st & 1) ? OFF_HN0 : OFF_HN1);
  float* __restrict__      hnT_nxt = wsf + ((st & 1) ? OFF_HT0 : OFF_HT1);

  const int tid = threadIdx.x, blk = blockIdx.x;
  const int lane = tid & 63;
  const int wv = __builtin_amdgcn_readfirstlane(tid >> 6);
  const int jg = blk & 15, bg = blk >> 4;
  const int j0 = jg << 6, b0 = bg << 2;

  int ptrs[4] = {0, 0, 0, 0};
  if (wv >= 8) {                                 // only s2a half needs ptrs
    const float2* cp = (const float2*)(wsf + OFF_CAND);
    #pragma unroll
    for (int i = 0; i < 4; ++i) {
      const float2* row = cp + (size_t)(b0 + i) * 256;
      float2 c0 = row[lane];
      float bv = c0.x; int bi = __float_as_int(c0.y);
      #pragma unroll
      for (int q = 1; q < 4; ++q) {
        float2 c = row[q * 64 + lane];
        if (c.x > bv) { bv = c.x; bi = __float_as_int(c.y); }
      }
      #pragma unroll
      for (int off = 1; off <= 32; off <<= 1) {
        float ov = __shfl_xor(bv, off);
        int   oi = __shfl_xor(bi, off);
        if (ov > bv || (ov == bv && oi < bi)) { bv = ov; bi = oi; }
      }
      ptrs[i] = __builtin_amdgcn_readfirstlane(bi);
    }
  }
  int done = 0;
  for (int tt = 0; tt < st; ++tt) done |= (ctrl[2 + tt] == NB) ? 1 : 0;

  const int kb = wv << 7;                        // 128 k per wave
  const float *p0, *p1, *p2, *p3;                // wave-uniform bases
  if (wv < 8) {
    p0 = hn_cur + (size_t)(b0 + 0) * NH + kb;
    p1 = hn_cur + (size_t)(b0 + 1) * NH + kb;
    p2 = hn_cur + (size_t)(b0 + 2) * NH + kb;
    p3 = hn_cur + (size_t)(b0 + 3) * NH + kb;
  } else {
    p0 = s2a + ((size_t)(b0 + 0) * NS + ptrs[0]) * NH + (kb - NH);
    p1 = s2a + ((size_t)(b0 + 1) * NS + ptrs[1]) * NH + (kb - NH);
    p2 = s2a + ((size_t)(b0 + 2) * NS + ptrs[2]) * NH + (kb - NH);
    p3 = s2a + ((size_t)(b0 + 3) * NS + ptrs[3]) * NH + (kb - NH);
  }
  const float* wp = Wres + (size_t)kb * NH + j0 + lane;   // per-lane

  float a0 = 0.f, a1 = 0.f, a2 = 0.f, a3 = 0.f;

  #pragma unroll 1
  for (int kc = 0; kc < 128; kc += 8) {
    float w[8];
    f4v q0[2], q1[2], q2[2], q3[2];
    #pragma unroll
    for (int i = 0; i < 8; ++i) w[i] = wp[(size_t)(kc + i) * NH];
    #pragma unroll
    for (int i = 0; i < 2; ++i) {
      q0[i] = *(const f4v*)(p0 + kc + 4 * i);
      q1[i] = *(const f4v*)(p1 + kc + 4 * i);
      q2[i] = *(const f4v*)(p2 + kc + 4 * i);
      q3[i] = *(const f4v*)(p3 + kc + 4 * i);
    }
    #pragma unroll
    for (int i = 0; i < 8; ++i) {
      const float wv_ = w[i];
      a0 += q0[i >> 2][i & 3] * wv_;
      a1 += q1[i >> 2][i & 3] * wv_;
      a2 += q2[i >> 2][i & 3] * wv_;
      a3 += q3[i >> 2][i & 3] * wv_;
    }
  }

  // cross-wave reduce: red[16 w][4 b][64 j]
  smem[wv * 256 + 0 * 64 + lane] = a0;
  smem[wv * 256 + 1 * 64 + lane] = a1;
  smem[wv * 256 + 2 * 64 + lane] = a2;
  smem[wv * 256 + 3 * 64 + lane] = a3;
  __syncthreads();

  if (tid < 256) {
    const int bsel = tid >> 6, jloc = tid & 63;
    float v = bres[j0 + jloc];
    #pragma unroll
    for (int w = 0; w < 16; ++w) v += smem[w * 256 + bsel * 64 + jloc];
    const int b = b0 + bsel, j = j0 + jloc;
    float hold = h[(size_t)b * NH + j];
    float hout = done ? hold : v;
    h[(size_t)b * NH + j] = hout;
    if (st < NSTEP - 1) {
      float hnv = hout + 0.01f * noise[(size_t)(st + 1) * (NB * NH) + (size_t)b * NH + j];
      hn_nxt[(size_t)b * NH + j] = hnv;
      hnT_nxt[((size_t)(j >> 1)) * 128 + b * 2 + (j & 1)] = hnv;
      const float* wrp = Wop + (size_t)j * NOPSN;
      float opo[8];
      #pragma unroll
      for (int o = 0; o < 8; ++o) opo[o] = hnv * wrp[o];
      #pragma unroll
      for (int off = 1; off <= 32; off <<= 1) {
        #pragma unroll
        for (int o = 0; o < 8; ++o) opo[o] += __shfl_xor(opo[o], off);
      }
      if ((tid & 63) == 0) {
        float* od = opp + ((size_t)(st + 1) * 16 + jg) * 512 + (size_t)b * 8;
        #pragma unroll
        for (int o = 0; o < 8; ++o) od[o] = opo[o];
      }
    } else {
      out[(size_t)b * NH + j] = hout;
    }
  }
}

extern "C" void kernel_launch(void* const* d_in, const int* in_sizes, int n_in,
                              void* d_out, int out_size, void* d_ws, size_t ws_size,
                              hipStream_t stream) {
  const float* s2a   = (const float*)d_in[0];
  const float* Wres  = (const float*)d_in[1];
  const float* bres  = (const float*)d_in[2];
  const float* Wop   = (const float*)d_in[3];
  const float* bop   = (const float*)d_in[4];
  const float* Wx    = (const float*)d_in[5];
  const float* bx    = (const float*)d_in[6];
  const float* noise = (const float*)d_in[7];
  float* outp = (float*)d_out;
  float* wsf  = (float*)d_ws;   // needs ~1.8 MB

  hipLaunchKernelGGL(init_kernel, dim3(64), dim3(1024), 0, stream,
                     noise, Wop, wsf);
  for (int st = 0; st < NSTEP; ++st) {
    hipLaunchKernelGGL(phaseA_kernel, dim3(256), dim3(1024), 0, stream,
                       Wx, bx, bop, wsf, st);
    hipLaunchKernelGGL(phaseC_kernel, dim3(256), dim3(1024), 0, stream,
                       s2a, Wres, bres, Wop, noise, outp, wsf, st);
  }
}

// Round 11
// 1671.147 us; speedup vs baseline: 1.4547x; 1.1160x over previous
//
#include <hip/hip_runtime.h>
#include <cstdint>
#include <cstddef>

// Problem constants
#define NB    64      // batch
#define NS    4096    // seq len
#define NH    1024    // hidden
#define NOPSN 8
#define NSTEP 10

// Workspace layout (float offsets), ~1.9 MB.
// hn/hnT double-buffered by step parity; hnT = k-pair interleave:
// element (k,b) at [(k>>1)*128 + b*2 + (k&1)]
#define OFF_HN0  0u
#define OFF_HN1  65536u
#define OFF_HT0  131072u
#define OFF_HT1  196608u
#define OFF_H    262144u
#define OFF_CAND 327680u   // cand [64 b][512 blk] float2 (val, idx-as-float)
#define OFF_OPP  393216u   // opp [10][16 jg][64 b][8 o]
#define OFF_CTRL 475136u   // ints: [2..11]=stopcnt[t]

typedef float f2v  __attribute__((ext_vector_type(2)));
typedef float f4v  __attribute__((ext_vector_type(4)));
typedef float f8v  __attribute__((ext_vector_type(8)));

__device__ __forceinline__ float bcastf(float v, int l) {
  return __int_as_float(__builtin_amdgcn_readlane(__float_as_int(v), l));
}

// ============ INIT: hn(0)=0.01*noise[0], hnT(0), h=0, opp[0], ctrl=0 ======
// grid 64 (block = b), 1024 threads (thread = j). Wave wv == jg.
__global__ void __launch_bounds__(1024)
init_kernel(const float* __restrict__ noise, const float* __restrict__ Wop,
            float* __restrict__ wsf)
{
  const int b = blockIdx.x, j = threadIdx.x;
  const int lane = j & 63, jg = j >> 6;
  int* ctrl = (int*)(wsf + OFF_CTRL);
  if (b == 0 && j < NSTEP) ctrl[2 + j] = 0;

  float hv = 0.01f * noise[(size_t)b * NH + j];
  (wsf + OFF_HN0)[(size_t)b * NH + j] = hv;
  (wsf + OFF_HT0)[((size_t)(j >> 1)) * 128 + b * 2 + (j & 1)] = hv;
  (wsf + OFF_H)[(size_t)b * NH + j] = 0.f;

  const float* wrp = Wop + (size_t)j * NOPSN;
  float opo[8];
  #pragma unroll
  for (int o = 0; o < 8; ++o) opo[o] = hv * wrp[o];
  #pragma unroll
  for (int off = 1; off <= 32; off <<= 1) {
    #pragma unroll
    for (int o = 0; o < 8; ++o) opo[o] += __shfl_xor(opo[o], off);
  }
  if (lane == 0) {
    float* od = (wsf + OFF_OPP) + (size_t)jg * 512 + (size_t)b * 8;
    #pragma unroll
    for (int o = 0; o < 8; ++o) od[o] = opo[o];
  }
}

// ============ PHASE A: x_logits[8 s][64 b] + cand + op-argmax =============
// grid 512 (block = 8 s-cols), 1024 thr, 32 KB LDS -> 2 blocks/CU,
// 8 waves/SIMD (2x the TLP of R10). lane = b; wave = 64-k slice.
__global__ void __launch_bounds__(1024, 8)
phaseA_kernel(const float* __restrict__ Wx, const float* __restrict__ bx,
              const float* __restrict__ bop, float* __restrict__ wsf, int st)
{
  __shared__ float smem[8192];   // 32 KB: [16 w][8 s][64 b]
  int* ctrl = (int*)(wsf + OFF_CTRL);
  float* __restrict__ opp = wsf + OFF_OPP;
  const float* __restrict__ hnT_cur = wsf + ((st & 1) ? OFF_HT1 : OFF_HT0);

  const int tid = threadIdx.x, blk = blockIdx.x;
  const int lane = tid & 63;
  const int wv = __builtin_amdgcn_readfirstlane(tid >> 6);
  const int s0A = blk << 3;
  const int kbaseA = wv << 6;

  const float2* hb = (const float2*)hnT_cur + ((size_t)(kbaseA >> 1)) * 64 + lane;

  // op-argmax for step st (blocks 0..63, wave 0)
  if (blk < NB && tid < 64) {
    const float* ob = opp + (size_t)st * 8192 + (size_t)blk * 8;
    const int o = lane & 7, jgb = lane >> 3;
    float v = ob[(size_t)jgb * 512 + o] + ob[(size_t)(jgb + 8) * 512 + o];
    v += __shfl_xor(v, 8);
    v += __shfl_xor(v, 16);
    v += __shfl_xor(v, 32);
    v += bop[o];
    float bv = bcastf(v, 0); int bo = 0;
    #pragma unroll
    for (int oo = 1; oo < 8; ++oo) {
      float vo = bcastf(v, oo);
      if (vo > bv) { bv = vo; bo = oo; }            // strict > : first-max
    }
    if (lane == 0 && bo == 0) atomicAdd(&ctrl[2 + st], 1);
  }

  float acc[8];
  #pragma unroll
  for (int s = 0; s < 8; ++s) acc[s] = 0.f;

  #pragma unroll 1
  for (int c = 0; c < 4; ++c) {
    float2 hh[8];
    #pragma unroll
    for (int i = 0; i < 8; ++i) hh[i] = hb[(size_t)(c * 8 + i) * 64];
    #pragma unroll
    for (int i = 0; i < 8; ++i) {
      const int k = kbaseA + (c * 8 + i) * 2;
      const f8v w0 = *(const f8v*)(Wx + (size_t)k * NS + s0A);
      const f8v w1 = *(const f8v*)(Wx + (size_t)(k + 1) * NS + s0A);
      #pragma unroll
      for (int s = 0; s < 8; ++s)
        acc[s] += w0[s] * hh[i].x + w1[s] * hh[i].y;
    }
  }

  // cross-wave K reduction: red[16 w][8 s][64 b]
  #pragma unroll
  for (int s = 0; s < 8; ++s)
    smem[wv * 512 + s * 64 + lane] = acc[s];
  __syncthreads();
  {
    const int s = tid >> 6, b = tid & 63;           // s in [0,16), valid < 8
    float val = 0.f;
    if (s < 8) {
      val = bx[s0A + s];
      #pragma unroll
      for (int w = 0; w < 16; ++w) val += smem[w * 512 + s * 64 + b];
    }
    __syncthreads();
    if (s < 8) smem[s * 64 + b] = val;
    __syncthreads();
    if (tid < 64) {
      const int bb = tid;
      float bv = smem[bb]; int bs = 0;
      #pragma unroll
      for (int s2 = 1; s2 < 8; ++s2) {
        float v2 = smem[s2 * 64 + bb];
        if (v2 > bv) { bv = v2; bs = s2; }          // ascending s: first-max
      }
      float2* cp = (float2*)(wsf + OFF_CAND);
      cp[bb * 512 + blk] = make_float2(bv, __int_as_float(s0A + bs));
    }
  }
}

// ============ PHASE C: h_new + freeze + next hn/hnT/opp (+ out) ===========
// grid 512: block (jg: 64 j, bg: 2 b), 1024 thr, 8 KB LDS -> 2 blocks/CU.
__global__ void __launch_bounds__(1024, 8)
phaseC_kernel(const float* __restrict__ s2a,  const float* __restrict__ Wres,
              const float* __restrict__ bres, const float* __restrict__ Wop,
              const float* __restrict__ noise, float* __restrict__ out,
              float* __restrict__ wsf, int st)
{
  __shared__ float smem[2048];   // 8 KB: [16 w][2 b][64 j]
  int* ctrl = (int*)(wsf + OFF_CTRL);
  float* __restrict__ h   = wsf + OFF_H;
  float* __restrict__ opp = wsf + OFF_OPP;
  const float* __restrict__ hn_cur = wsf + ((st & 1) ? OFF_HN1 : OFF_HN0);
  float* __restrict__       hn_nxt = wsf + ((st & 1) ? OFF_HN0 : OFF_HN1);
  float* __restrict__      hnT_nxt = wsf + ((st & 1) ? OFF_HT0 : OFF_HT1);

  const int tid = threadIdx.x, blk = blockIdx.x;
  const int lane = tid & 63;
  const int wv = __builtin_amdgcn_readfirstlane(tid >> 6);
  const int jg = blk & 15, bg = blk >> 4;          // bg in [0,32)
  const int j0 = jg << 6, b0 = bg << 1;            // 2 b per block

  int ptrs[2] = {0, 0};
  if (wv >= 8) {                                   // only s2a half needs ptrs
    const float2* cp = (const float2*)(wsf + OFF_CAND);
    #pragma unroll
    for (int i = 0; i < 2; ++i) {
      const float2* row = cp + (size_t)(b0 + i) * 512;
      float2 c0 = row[lane];
      float bv = c0.x; int bi = __float_as_int(c0.y);
      #pragma unroll
      for (int q = 1; q < 8; ++q) {
        float2 c = row[q * 64 + lane];
        if (c.x > bv) { bv = c.x; bi = __float_as_int(c.y); }
      }
      #pragma unroll
      for (int off = 1; off <= 32; off <<= 1) {
        float ov = __shfl_xor(bv, off);
        int   oi = __shfl_xor(bi, off);
        if (ov > bv || (ov == bv && oi < bi)) { bv = ov; bi = oi; }
      }
      ptrs[i] = __builtin_amdgcn_readfirstlane(bi);
    }
  }
  int done = 0;
  for (int tt = 0; tt < st; ++tt) done |= (ctrl[2 + tt] == NB) ? 1 : 0;

  const int kb = wv << 7;                          // 128 k per wave
  const float *p0, *p1;                            // wave-uniform bases
  if (wv < 8) {
    p0 = hn_cur + (size_t)(b0 + 0) * NH + kb;
    p1 = hn_cur + (size_t)(b0 + 1) * NH + kb;
  } else {
    p0 = s2a + ((size_t)(b0 + 0) * NS + ptrs[0]) * NH + (kb - NH);
    p1 = s2a + ((size_t)(b0 + 1) * NS + ptrs[1]) * NH + (kb - NH);
  }
  const float* wp = Wres + (size_t)kb * NH + j0 + lane;   // per-lane

  float a0 = 0.f, a1 = 0.f;

  #pragma unroll 1
  for (int kc = 0; kc < 128; kc += 8) {
    float w[8];
    f4v q0[2], q1[2];
    #pragma unroll
    for (int i = 0; i < 8; ++i) w[i] = wp[(size_t)(kc + i) * NH];
    #pragma unroll
    for (int i = 0; i < 2; ++i) {
      q0[i] = *(const f4v*)(p0 + kc + 4 * i);
      q1[i] = *(const f4v*)(p1 + kc + 4 * i);
    }
    #pragma unroll
    for (int i = 0; i < 8; ++i) {
      const float wv_ = w[i];
      a0 += q0[i >> 2][i & 3] * wv_;
      a1 += q1[i >> 2][i & 3] * wv_;
    }
  }

  // cross-wave reduce: red[16 w][2 b][64 j]
  smem[wv * 128 + 0 * 64 + lane] = a0;
  smem[wv * 128 + 1 * 64 + lane] = a1;
  __syncthreads();

  if (tid < 128) {
    const int bsel = tid >> 6, jloc = tid & 63;
    float v = bres[j0 + jloc];
    #pragma unroll
    for (int w = 0; w < 16; ++w) v += smem[w * 128 + bsel * 64 + jloc];
    const int b = b0 + bsel, j = j0 + jloc;
    float hold = h[(size_t)b * NH + j];
    float hout = done ? hold : v;
    h[(size_t)b * NH + j] = hout;
    if (st < NSTEP - 1) {
      float hnv = hout + 0.01f * noise[(size_t)(st + 1) * (NB * NH) + (size_t)b * NH + j];
      hn_nxt[(size_t)b * NH + j] = hnv;
      hnT_nxt[((size_t)(j >> 1)) * 128 + b * 2 + (j & 1)] = hnv;
      const float* wrp = Wop + (size_t)j * NOPSN;
      float opo[8];
      #pragma unroll
      for (int o = 0; o < 8; ++o) opo[o] = hnv * wrp[o];
      #pragma unroll
      for (int off = 1; off <= 32; off <<= 1) {
        #pragma unroll
        for (int o = 0; o < 8; ++o) opo[o] += __shfl_xor(opo[o], off);
      }
      if ((tid & 63) == 0) {
        float* od = opp + ((size_t)(st + 1) * 16 + jg) * 512 + (size_t)b * 8;
        #pragma unroll
        for (int o = 0; o < 8; ++o) od[o] = opo[o];
      }
    } else {
      out[(size_t)b * NH + j] = hout;
    }
  }
}

extern "C" void kernel_launch(void* const* d_in, const int* in_sizes, int n_in,
                              void* d_out, int out_size, void* d_ws, size_t ws_size,
                              hipStream_t stream) {
  const float* s2a   = (const float*)d_in[0];
  const float* Wres  = (const float*)d_in[1];
  const float* bres  = (const float*)d_in[2];
  const float* Wop   = (const float*)d_in[3];
  const float* bop   = (const float*)d_in[4];
  const float* Wx    = (const float*)d_in[5];
  const float* bx    = (const float*)d_in[6];
  const float* noise = (const float*)d_in[7];
  float* outp = (float*)d_out;
  float* wsf  = (float*)d_ws;   // needs ~1.9 MB

  hipLaunchKernelGGL(init_kernel, dim3(64), dim3(1024), 0, stream,
                     noise, Wop, wsf);
  for (int st = 0; st < NSTEP; ++st) {
    hipLaunchKernelGGL(phaseA_kernel, dim3(512), dim3(1024), 0, stream,
                       Wx, bx, bop, wsf, st);
    hipLaunchKernelGGL(phaseC_kernel, dim3(512), dim3(1024), 0, stream,
                       s2a, Wres, bres, Wop, noise, outp, wsf, st);
  }
}